// Round 8
// baseline (616.553 us; speedup 1.0000x reference)
//
#include <hip/hip_runtime.h>
#include <hip/hip_bf16.h>
#include <stdint.h>

#define NROWS 65536   // B*S = 16*4096
#define DDIM  256
#define KCAND 4096
#define CAP   48      // per-row candidate list slots
#define MARGIN1 8e-4f // phase-1 collect margin (worst-case bf16 err 2*2.2e-4 + tie grid)
#define MARGIN2 8e-4f // phase-2 prune margin

#define LSTRIDE 132   // LDS row stride in dwords (528B: 16B-aligned)
#define ROWS_PB 128   // rows per phase-1 block

typedef __bf16 bf16x8 __attribute__((ext_vector_type(8)));
typedef float  f32x4  __attribute__((ext_vector_type(4)));
typedef unsigned int u32;
typedef unsigned long long u64;

__device__ __forceinline__ u32 f2bf_u(float f) {
    u32 u = __float_as_uint(f);
    u += 0x7fffu + ((u >> 16) & 1u);
    return u >> 16;
}
__device__ __forceinline__ u32 pack2(float lo, float hi) { return f2bf_u(lo) | (f2bf_u(hi) << 16); }
__device__ __forceinline__ u32 fkey(float f) {
    u32 u = __float_as_uint(f);
    return (u & 0x80000000u) ? ~u : (u | 0x80000000u);
}
__device__ __forceinline__ float funkey(u32 k) {
    u32 u = (k & 0x80000000u) ? (k ^ 0x80000000u) : ~k;
    return __uint_as_float(u);
}
__device__ __forceinline__ float vmax4(f32x4 v) {
    return fmaxf(fmaxf(v[0], v[1]), fmaxf(v[2], v[3]));
}

// np-semantics exact distance: r = fl(fl(A + b_k) - acc_k), sequential ascending-d
// FMA chain. float4 loads only widen the LOADS; fp op order identical to scalar.
__device__ __forceinline__ float exact_r4(const float* __restrict__ xr, float A,
                                          const float* __restrict__ er) {
    float b = 0.f, acc = 0.f;
    #pragma unroll 8
    for (int q = 0; q < DDIM / 4; ++q) {
        float4 e  = ((const float4*)er)[q];
        float4 xv = ((const float4*)xr)[q];
        b = fmaf(e.x, e.x, b);  acc = fmaf(2.0f * xv.x, e.x, acc);
        b = fmaf(e.y, e.y, b);  acc = fmaf(2.0f * xv.y, e.y, acc);
        b = fmaf(e.z, e.z, b);  acc = fmaf(2.0f * xv.z, e.z, acc);
        b = fmaf(e.w, e.w, b);  acc = fmaf(2.0f * xv.w, e.w, acc);
    }
    return (A + b) - acc;
}

// ---------------------------------------------------------------- convert
__launch_bounds__(256)
__global__ void convert_e(const float* __restrict__ e, u32* __restrict__ ebf) {
    int T = blockIdx.x * blockDim.x + threadIdx.x;   // 131072 = 64 s * 8 kc * 4 u * 64 L
    int L = T & 63, u = (T >> 6) & 3, kc = (T >> 8) & 7, s = T >> 11;
    int cand = s * 64 + u * 16 + (L & 15);
    int k0 = kc * 32 + (L >> 4) * 8;
    const float4* src = (const float4*)(e + (size_t)cand * DDIM + k0);
    float4 a = src[0], b = src[1];
    uint4 o;
    o.x = pack2(a.x, a.y); o.y = pack2(a.z, a.w);
    o.z = pack2(b.x, b.y); o.w = pack2(b.z, b.w);
    ((uint4*)ebf)[T] = o;
}

// ---------------------------------------------------------------- phase 1
// R6's proven body (268us, no spill) + 2-it prepass + FAST-PATH-ONLY tail.
// NO exact_r in this kernel (R7 lesson: fusing it spills the main loop).
// Tail prefetches cnt/list[0] lane-parallel (lanes 0..31 hold rows 0..31,
// shuffled per row) to kill 32 serial cnt->list latency chains.
__launch_bounds__(256, 2)
__global__ void phase1(const float* __restrict__ x, const u32* __restrict__ ebf,
                       const float* __restrict__ emb,
                       u32* __restrict__ cnt, uint2* __restrict__ list,
                       float* __restrict__ outq, float* __restrict__ outp) {
    __shared__ u32 lxd[ROWS_PB * LSTRIDE];   // 128 rows x 132 dwords
    __shared__ u32 rowBestK[ROWS_PB];        // fkey(row acc-max), monotone under atomicMax

    const int tid = threadIdx.x;
    const int rowBase = blockIdx.x * ROWS_PB;
    if (tid < ROWS_PB) rowBestK[tid] = 0x007FFFFFu;   // fkey(-inf)

    // stage x tile once: fp32 -> bf16, linear rows (stride 132 dwords)
    {
        const float4* x4 = (const float4*)(x + (size_t)rowBase * DDIM);
        #pragma unroll
        for (int j = 0; j < 32; ++j) {
            int idx = j * 256 + tid;
            int r = idx >> 6, c4 = idx & 63;
            float4 v = x4[idx];
            *(uint2*)&lxd[r * LSTRIDE + 2 * c4] = make_uint2(pack2(v.x, v.y), pack2(v.z, v.w));
        }
    }
    __syncthreads();

    const int L = tid & 63;
    const int w = __builtin_amdgcn_readfirstlane(tid >> 6);
    const int lq = L >> 4, ln = L & 15;
    const int vL = L << 4;

    const char* ebc_w = (const char*)ebf + (size_t)w * 32768;

    auto loadB = [&](int it_, int kc_, bf16x8* dst) {
        const char* kb = ebc_w + (size_t)it_ * 131072 + kc_ * 4096;
        #pragma unroll
        for (int u = 0; u < 4; ++u)
            dst[u] = *(const bf16x8*)(kb + u * 1024 + vL);
    };

    const char* pa = (const char*)lxd + ln * (LSTRIDE * 4) + lq * 16;

    bf16x8 bb[2][4];
    f32x4 acc[8][4];
    const f32x4 Z4 = {0.f, 0.f, 0.f, 0.f};

    // ---- PRE-PASS: its 0..1 (cands 0..511) maxes only, seeds rowBestK ----
    loadB(0, 0, bb[0]);
    #pragma unroll 1
    for (int pit = 0; pit < 2; ++pit) {
        {
            loadB(pit, 1, bb[1]);
            #pragma unroll
            for (int a = 0; a < 8; ++a) {
                bf16x8 fa = *(const bf16x8*)(pa + a * (16 * LSTRIDE * 4));
                #pragma unroll
                for (int u = 0; u < 4; ++u)
                    acc[a][u] = __builtin_amdgcn_mfma_f32_16x16x32_bf16(bb[0][u], fa, Z4, 0, 0, 0);
            }
        }
        #pragma unroll
        for (int kc = 1; kc < 8; ++kc) {
            int g = pit * 8 + kc;
            if (g < 15) { int gn = g + 1; loadB(gn >> 3, gn & 7, bb[(kc + 1) & 1]); }
            #pragma unroll
            for (int a = 0; a < 8; ++a) {
                bf16x8 fa = *(const bf16x8*)(pa + a * (16 * LSTRIDE * 4) + kc * 64);
                #pragma unroll
                for (int u = 0; u < 4; ++u)
                    acc[a][u] = __builtin_amdgcn_mfma_f32_16x16x32_bf16(bb[kc & 1][u], fa, acc[a][u], 0, 0, 0);
            }
        }
        #pragma unroll
        for (int a = 0; a < 8; ++a) {
            float lmax = fmaxf(fmaxf(vmax4(acc[a][0]), vmax4(acc[a][1])),
                               fmaxf(vmax4(acc[a][2]), vmax4(acc[a][3])));
            float m = fmaxf(lmax, __shfl_xor(lmax, 16, 64));
            m = fmaxf(m, __shfl_xor(m, 32, 64));
            if (lq == 0) atomicMax(&rowBestK[a * 16 + ln], fkey(m));
        }
    }
    __syncthreads();   // seeds visible before any collection

    // ---- MAIN LOOP: it=0..15 with collection ----
    loadB(0, 0, bb[0]);
    #pragma unroll 1
    for (int it = 0; it < 16; ++it) {
        {
            loadB(it, 1, bb[1]);
            #pragma unroll
            for (int a = 0; a < 8; ++a) {
                bf16x8 fa = *(const bf16x8*)(pa + a * (16 * LSTRIDE * 4));
                #pragma unroll
                for (int u = 0; u < 4; ++u)
                    acc[a][u] = __builtin_amdgcn_mfma_f32_16x16x32_bf16(bb[0][u], fa, Z4, 0, 0, 0);
            }
        }
        #pragma unroll
        for (int kc = 1; kc < 8; ++kc) {
            int g = it * 8 + kc;
            if (g < 127) { int gn = g + 1; loadB(gn >> 3, gn & 7, bb[(kc + 1) & 1]); }
            #pragma unroll
            for (int a = 0; a < 8; ++a) {
                bf16x8 fa = *(const bf16x8*)(pa + a * (16 * LSTRIDE * 4) + kc * 64);
                #pragma unroll
                for (int u = 0; u < 4; ++u)
                    acc[a][u] = __builtin_amdgcn_mfma_f32_16x16x32_bf16(bb[kc & 1][u], fa, acc[a][u], 0, 0, 0);
            }
        }

        int strip = it * 4 + w;
        u32 seen[8];
        #pragma unroll
        for (int a = 0; a < 8; ++a) seen[a] = rowBestK[a * 16 + ln];

        #pragma unroll
        for (int a = 0; a < 8; ++a) {
            float lmax = fmaxf(fmaxf(vmax4(acc[a][0]), vmax4(acc[a][1])),
                               fmaxf(vmax4(acc[a][2]), vmax4(acc[a][3])));
            float m = fmaxf(lmax, __shfl_xor(lmax, 16, 64));
            m = fmaxf(m, __shfl_xor(m, 32, 64));
            if (lq == 0) atomicMax(&rowBestK[a * 16 + ln], fkey(m));
            float eff  = fmaxf(m, funkey(seen[a]));
            float thrA = eff - 0.5f * MARGIN1;
            if (__ballot(lmax >= thrA)) {
                int c = 0;
                #pragma unroll
                for (int u = 0; u < 4; ++u)
                    #pragma unroll
                    for (int r = 0; r < 4; ++r)
                        c += (acc[a][u][r] >= thrA) ? 1 : 0;
                int p = c, t;
                t = __shfl_up(p, 16, 64); if (lq >= 1) p += t;
                t = __shfl_up(p, 32, 64); if (lq >= 2) p += t;
                int grow = rowBase + a * 16 + ln;
                u32 base = 0;
                if (lq == 3 && p > 0) base = atomicAdd(&cnt[grow], (u32)p);
                base = __shfl(base, 48 + ln, 64);
                u32 pos = base + (u32)(p - c);
                #pragma unroll
                for (int u = 0; u < 4; ++u)
                    #pragma unroll
                    for (int r = 0; r < 4; ++r) {
                        float av = acc[a][u][r];
                        if (av >= thrA) {
                            if (pos < CAP)
                                list[(size_t)grow * CAP + pos] =
                                    make_uint2(__float_as_uint(-2.f * av),
                                               (u32)(strip * 64 + u * 16 + lq * 4 + r));
                            ++pos;
                        }
                    }
            }
        }
    }

    // ---- FAST-PATH RESOLVE TAIL (no exact_r here) ----
    __syncthreads();

    {
        int myrow = rowBase + w * 32 + (L & 31);
        u32 nv = cnt[myrow];                       // lane-parallel prefetch
        uint2 e0 = list[(size_t)myrow * CAP];      // first entry (n>=1 always)

        for (int rr = 0; rr < 32; ++rr) {
            int grow = rowBase + w * 32 + rr;
            u32 n = __shfl(nv, rr, 64);
            u32 kstar = __shfl(e0.y, rr, 64);
            bool resolved = (n == 1);
            if (!resolved && n <= CAP) {
                float vv = INFINITY; u32 kk = 0;
                if (L < (int)n) { uint2 e = list[(size_t)grow * CAP + L]; vv = __uint_as_float(e.x); kk = e.y; }
                float mv = vv;
                #pragma unroll
                for (int o = 32; o; o >>= 1) mv = fminf(mv, __shfl_xor(mv, o, 64));
                bool surv = (L < (int)n) && (vv <= mv + MARGIN2);
                u64 bal = __ballot(surv);
                if (__popcll(bal) == 1) {          // unique margin-survivor = exact winner
                    kstar = __shfl(kk, (int)(__ffsll(bal) - 1), 64);
                    resolved = true;
                }
            }
            if (resolved) {
                float4 q = ((const float4*)(emb + (size_t)kstar * DDIM))[L];
                ((float4*)(outq + (size_t)grow * DDIM))[L] = q;
                if (L == 0) { outp[grow] = (float)kstar; cnt[grow] = 0; }  // 0 = done
            }
            // unresolved: cnt stays n -> rescue kernel
        }
    }
}

// ---------------------------------------------------------------- rescue (cooperative)
// 4096 blocks x 16 rows. Block compacts active rows to a shared queue.
// Tie rows (n<=CAP): wave 0, one exact_r4 per survivor lane. Overflow rows
// (n>CAP): ALL 256 threads scan 16 cands each -> a former 170us serial bomb
// costs ~7us and bombs are block-parallel. np-bit-exact, same tie-break.
__launch_bounds__(256)
__global__ void rescue(const float* __restrict__ x, const float* __restrict__ emb,
                       const u32* __restrict__ cnt, const uint2* __restrict__ list,
                       float* __restrict__ outq, float* __restrict__ outp) {
    __shared__ float xs[DDIM];
    __shared__ u32 rowl[16];
    __shared__ int nact_s;
    __shared__ float A_s;
    __shared__ u64 best[4];

    const int tid = threadIdx.x;
    const int base = blockIdx.x * 16;
    if (tid == 0) nact_s = 0;
    __syncthreads();
    if (tid < 16 && cnt[base + tid] != 0) {
        int p = atomicAdd(&nact_s, 1);
        rowl[p] = (u32)(base + tid);
    }
    __syncthreads();
    const int nact = nact_s;
    if (nact == 0) return;

    const int L = tid & 63;
    const int wv = tid >> 6;

    for (int i = 0; i < nact; ++i) {
        const int row = (int)rowl[i];
        const u32 n = cnt[row];

        // stage x row + A = |x|^2 (np-identical double butterfly on wave 0)
        if (tid < 64) {
            float4 xv = ((const float4*)(x + (size_t)row * DDIM))[tid];
            *(float4*)&xs[tid * 4] = xv;
            double s = (double)xv.x * xv.x + (double)xv.y * xv.y
                     + (double)xv.z * xv.z + (double)xv.w * xv.w;
            #pragma unroll
            for (int o = 32; o; o >>= 1) s += __shfl_xor(s, o, 64);
            if (tid == 0) A_s = (float)s;
        }
        __syncthreads();
        const float A = A_s;

        u64 key = 0xFFFFFFFFFFFFFFFFull;
        if (n <= CAP) {
            if (wv == 0) {
                float vv = INFINITY; u32 kk = 0;
                if (L < (int)n) { uint2 e = list[(size_t)row * CAP + L]; vv = __uint_as_float(e.x); kk = e.y; }
                float mv = vv;
                #pragma unroll
                for (int o = 32; o; o >>= 1) mv = fminf(mv, __shfl_xor(mv, o, 64));
                if (L < (int)n && vv <= mv + MARGIN2) {
                    float r = exact_r4(xs, A, emb + (size_t)kk * DDIM);
                    key = ((u64)fkey(r) << 32) | (u64)kk;
                }
                #pragma unroll
                for (int o = 32; o; o >>= 1) {
                    u64 other = __shfl_xor(key, o, 64);
                    key = (other < key) ? other : key;
                }
                if (L == 0) best[0] = key;
            }
            __syncthreads();
            key = best[0];
        } else {
            // full 4096-cand exact scan, 16 cands per thread
            #pragma unroll 1
            for (int c = 0; c < KCAND / 256; ++c) {
                u32 k = (u32)(c * 256 + tid);
                float r = exact_r4(xs, A, emb + (size_t)k * DDIM);
                u64 cand = ((u64)fkey(r) << 32) | (u64)k;
                key = (cand < key) ? cand : key;
            }
            #pragma unroll
            for (int o = 32; o; o >>= 1) {
                u64 other = __shfl_xor(key, o, 64);
                key = (other < key) ? other : key;
            }
            if (L == 0) best[wv] = key;
            __syncthreads();
            if (tid == 0) {
                u64 b = best[0];
                b = (best[1] < b) ? best[1] : b;
                b = (best[2] < b) ? best[2] : b;
                b = (best[3] < b) ? best[3] : b;
                best[0] = b;
            }
            __syncthreads();
            key = best[0];
        }
        u32 kstar = (u32)(key & 0xFFFFFFFFull);

        if (tid < 64) {
            float4 q = ((const float4*)(emb + (size_t)kstar * DDIM))[tid];
            ((float4*)(outq + (size_t)row * DDIM))[tid] = q;
        }
        if (tid == 0) outp[row] = (float)kstar;
        __syncthreads();   // xs/best reused next iteration
    }
}

// ---------------------------------------------------------------- launch
extern "C" void kernel_launch(void* const* d_in, const int* in_sizes, int n_in,
                              void* d_out, int out_size, void* d_ws, size_t ws_size,
                              hipStream_t stream) {
    const float* x   = (const float*)d_in[0];   // [65536, 256] fp32
    const float* emb = (const float*)d_in[1];   // [4096, 256] fp32
    float* outq = (float*)d_out;                      // [65536,256]
    float* outp = outq + (size_t)NROWS * DDIM;        // [65536]

    char* ws = (char*)d_ws;
    u32*   ebf  = (u32*)ws;                           // 2 MB (strip-major bf16)
    u32*   cnt  = (u32*)(ws + (2u << 20));            // 256 KB
    uint2* list = (uint2*)(ws + (3u << 20));          // 24 MB (total 27 MB)

    hipMemsetAsync(cnt, 0, (size_t)NROWS * sizeof(u32), stream);
    convert_e<<<512, 256, 0, stream>>>(emb, ebf);
    phase1<<<NROWS / ROWS_PB, 256, 0, stream>>>(x, ebf, emb, cnt, list, outq, outp);
    rescue<<<NROWS / 16, 256, 0, stream>>>(x, emb, cnt, list, outq, outp);
}

// Round 9
// 390.333 us; speedup vs baseline: 1.5796x; 1.5796x over previous
//
#include <hip/hip_runtime.h>
#include <hip/hip_bf16.h>
#include <stdint.h>

#define NROWS 65536   // B*S = 16*4096
#define DDIM  256
#define KCAND 4096
#define CAP   48      // per-row candidate list slots
#define MARGIN1 8e-4f // phase-1 collect margin (worst-case bf16 err 2*2.2e-4 + tie grid)
#define MARGIN2 8e-4f // phase-2 prune margin

#define LSTRIDE 132   // LDS row stride in dwords (528B: 16B-aligned)
#define ROWS_PB 128   // rows per phase-1 block

typedef __bf16 bf16x8 __attribute__((ext_vector_type(8)));
typedef float  f32x4  __attribute__((ext_vector_type(4)));
typedef unsigned int u32;
typedef unsigned long long u64;

__device__ __forceinline__ u32 f2bf_u(float f) {
    u32 u = __float_as_uint(f);
    u += 0x7fffu + ((u >> 16) & 1u);
    return u >> 16;
}
__device__ __forceinline__ u32 pack2(float lo, float hi) { return f2bf_u(lo) | (f2bf_u(hi) << 16); }
__device__ __forceinline__ u32 fkey(float f) {
    u32 u = __float_as_uint(f);
    return (u & 0x80000000u) ? ~u : (u | 0x80000000u);
}
__device__ __forceinline__ float funkey(u32 k) {
    u32 u = (k & 0x80000000u) ? (k ^ 0x80000000u) : ~k;
    return __uint_as_float(u);
}
__device__ __forceinline__ float vmax4(f32x4 v) {
    return fmaxf(fmaxf(v[0], v[1]), fmaxf(v[2], v[3]));
}

// np-semantics exact distance: r = fl(fl(A + b_k) - acc_k), sequential ascending-d
// FMA chain. float4 only widens the LOADS (4x fewer load instrs); fp op order is
// IDENTICAL to the scalar version -> bit-exact vs np (validated on HW in R7/R8).
__device__ __forceinline__ float exact_r4(const float* __restrict__ xr, float A,
                                          const float* __restrict__ er) {
    float b = 0.f, acc = 0.f;
    #pragma unroll 8
    for (int q = 0; q < DDIM / 4; ++q) {
        float4 e  = ((const float4*)er)[q];
        float4 xv = ((const float4*)xr)[q];
        b = fmaf(e.x, e.x, b);  acc = fmaf(2.0f * xv.x, e.x, acc);
        b = fmaf(e.y, e.y, b);  acc = fmaf(2.0f * xv.y, e.y, acc);
        b = fmaf(e.z, e.z, b);  acc = fmaf(2.0f * xv.z, e.z, acc);
        b = fmaf(e.w, e.w, b);  acc = fmaf(2.0f * xv.w, e.w, acc);
    }
    return (A + b) - acc;
}

// ---------------------------------------------------------------- convert
// ebf strip-major for SGPR+imm addressing in phase1:
//   frag(s,kc,u): 1KB block at offset ((s*8+kc)*4+u)*1024; lane L's 16B at +L*16
//   holds cand = s*64 + u*16 + (L&15), k = kc*32 + (L>>4)*8  (8 bf16).
__launch_bounds__(256)
__global__ void convert_e(const float* __restrict__ e, u32* __restrict__ ebf) {
    int T = blockIdx.x * blockDim.x + threadIdx.x;   // 131072 = 64 s * 8 kc * 4 u * 64 L
    int L = T & 63, u = (T >> 6) & 3, kc = (T >> 8) & 7, s = T >> 11;
    int cand = s * 64 + u * 16 + (L & 15);
    int k0 = kc * 32 + (L >> 4) * 8;
    const float4* src = (const float4*)(e + (size_t)cand * DDIM + k0);
    float4 a = src[0], b = src[1];
    uint4 o;
    o.x = pack2(a.x, a.y); o.y = pack2(a.z, a.w);
    o.z = pack2(b.x, b.y); o.w = pack2(b.z, b.w);
    ((uint4*)ebf)[T] = o;
}

// ---------------------------------------------------------------- phase 1
// R4-current VERBATIM (measured 227us, clean counters, no spill).
// 256 thr = 4 waves, tile 128 rows x 4096 cands; x bf16 in LDS; e streamed
// to VGPRs (SGPR base + lane voffset + imm), double-buffered; strip = 64
// cands/wave/it; acc[8][4]; straight-line 1-it PRE-PASS seeds rowBestK.
// (Lesson R6-R8: ANY structural growth here -- looped prepass, fused tail --
// pushes regalloc past the 128V+128A cap and spills 100+ MB. Do not touch.)
__launch_bounds__(256, 2)
__global__ void phase1(const float* __restrict__ x, const u32* __restrict__ ebf,
                       u32* __restrict__ cnt, uint2* __restrict__ list) {
    __shared__ u32 lxd[ROWS_PB * LSTRIDE];   // 128 rows x 132 dwords
    __shared__ u32 rowBestK[ROWS_PB];        // fkey(row acc-max), monotone under atomicMax

    const int tid = threadIdx.x;
    const int rowBase = blockIdx.x * ROWS_PB;
    if (tid < ROWS_PB) rowBestK[tid] = 0x007FFFFFu;   // fkey(-inf)

    // stage x tile once: fp32 -> bf16, linear rows (stride 132 dwords)
    {
        const float4* x4 = (const float4*)(x + (size_t)rowBase * DDIM);
        #pragma unroll
        for (int j = 0; j < 32; ++j) {
            int idx = j * 256 + tid;          // 0..8191 float4 chunks
            int r = idx >> 6, c4 = idx & 63;
            float4 v = x4[idx];
            *(uint2*)&lxd[r * LSTRIDE + 2 * c4] = make_uint2(pack2(v.x, v.y), pack2(v.z, v.w));
        }
    }
    __syncthreads();

    const int L = tid & 63;
    const int w = __builtin_amdgcn_readfirstlane(tid >> 6);   // force SGPR
    const int lq = L >> 4, ln = L & 15;
    const int vL = L << 4;                                     // lane byte offset in frag

    const char* ebc_w = (const char*)ebf + (size_t)w * 32768;

    auto loadB = [&](int it_, int kc_, bf16x8* dst) {
        const char* kb = ebc_w + (size_t)it_ * 131072 + kc_ * 4096;
        #pragma unroll
        for (int u = 0; u < 4; ++u)
            dst[u] = *(const bf16x8*)(kb + u * 1024 + vL);
    };

    // fa: one VGPR address, all reads at compile-time ds offsets (max ~59.5KB)
    const char* pa = (const char*)lxd + ln * (LSTRIDE * 4) + lq * 16;

    bf16x8 bb[2][4];
    f32x4 acc[8][4];
    const f32x4 Z4 = {0.f, 0.f, 0.f, 0.f};

    // ---- PRE-PASS: it=0 maxes only, seeds rowBestK ----
    loadB(0, 0, bb[0]);
    #pragma unroll
    for (int kc = 0; kc < 8; ++kc) {
        if (kc < 7) loadB(0, kc + 1, bb[(kc + 1) & 1]);
        #pragma unroll
        for (int a = 0; a < 8; ++a) {
            bf16x8 fa = *(const bf16x8*)(pa + a * (16 * LSTRIDE * 4) + kc * 64);
            #pragma unroll
            for (int u = 0; u < 4; ++u)
                acc[a][u] = (kc == 0)
                    ? __builtin_amdgcn_mfma_f32_16x16x32_bf16(bb[0][u], fa, Z4, 0, 0, 0)
                    : __builtin_amdgcn_mfma_f32_16x16x32_bf16(bb[kc & 1][u], fa, acc[a][u], 0, 0, 0);
        }
    }
    #pragma unroll
    for (int a = 0; a < 8; ++a) {
        float lmax = fmaxf(fmaxf(vmax4(acc[a][0]), vmax4(acc[a][1])),
                           fmaxf(vmax4(acc[a][2]), vmax4(acc[a][3])));
        float m = fmaxf(lmax, __shfl_xor(lmax, 16, 64));
        m = fmaxf(m, __shfl_xor(m, 32, 64));
        if (lq == 0) atomicMax(&rowBestK[a * 16 + ln], fkey(m));
    }
    __syncthreads();   // seeds visible before any collection

    // ---- MAIN LOOP: it=0..15 with collection ----
    loadB(0, 0, bb[0]);   // re-load (L1/L2-hot)
    #pragma unroll 1
    for (int it = 0; it < 16; ++it) {
        // kc = 0 peeled: accumulator init via zero C-operand
        {
            loadB(it, 1, bb[1]);
            #pragma unroll
            for (int a = 0; a < 8; ++a) {
                bf16x8 fa = *(const bf16x8*)(pa + a * (16 * LSTRIDE * 4));
                #pragma unroll
                for (int u = 0; u < 4; ++u)
                    acc[a][u] = __builtin_amdgcn_mfma_f32_16x16x32_bf16(bb[0][u], fa, Z4, 0, 0, 0);
            }
        }
        #pragma unroll
        for (int kc = 1; kc < 8; ++kc) {
            int g = it * 8 + kc;
            if (g < 127) { int gn = g + 1; loadB(gn >> 3, gn & 7, bb[(kc + 1) & 1]); }
            #pragma unroll
            for (int a = 0; a < 8; ++a) {
                bf16x8 fa = *(const bf16x8*)(pa + a * (16 * LSTRIDE * 4) + kc * 64);
                #pragma unroll
                for (int u = 0; u < 4; ++u)
                    acc[a][u] = __builtin_amdgcn_mfma_f32_16x16x32_bf16(bb[kc & 1][u], fa, acc[a][u], 0, 0, 0);
            }
        }

        // epilogue for this strip (cands strip*64 .. +64), row-in-lane layout
        int strip = it * 4 + w;
        u32 seen[8];
        #pragma unroll
        for (int a = 0; a < 8; ++a) seen[a] = rowBestK[a * 16 + ln];   // broadcast reads, stale OK

        #pragma unroll
        for (int a = 0; a < 8; ++a) {
            float lmax = fmaxf(fmaxf(vmax4(acc[a][0]), vmax4(acc[a][1])),
                               fmaxf(vmax4(acc[a][2]), vmax4(acc[a][3])));
            float m = fmaxf(lmax, __shfl_xor(lmax, 16, 64));
            m = fmaxf(m, __shfl_xor(m, 32, 64));
            if (lq == 0) atomicMax(&rowBestK[a * 16 + ln], fkey(m));   // fire-and-forget
            float eff  = fmaxf(m, funkey(seen[a]));   // own strip folded in via register
            float thrA = eff - 0.5f * MARGIN1;        // acc-space threshold
            if (__ballot(lmax >= thrA)) {             // usually nothing fires
                int c = 0;
                #pragma unroll
                for (int u = 0; u < 4; ++u)
                    #pragma unroll
                    for (int r = 0; r < 4; ++r)
                        c += (acc[a][u][r] >= thrA) ? 1 : 0;
                int p = c, t;
                t = __shfl_up(p, 16, 64); if (lq >= 1) p += t;
                t = __shfl_up(p, 32, 64); if (lq >= 2) p += t;
                int grow = rowBase + a * 16 + ln;
                u32 base = 0;
                if (lq == 3 && p > 0) base = atomicAdd(&cnt[grow], (u32)p);  // 16 distinct rows
                base = __shfl(base, 48 + ln, 64);     // broadcast from lq==3 lane of this row
                u32 pos = base + (u32)(p - c);
                #pragma unroll
                for (int u = 0; u < 4; ++u)
                    #pragma unroll
                    for (int r = 0; r < 4; ++r) {
                        float av = acc[a][u][r];
                        if (av >= thrA) {
                            if (pos < CAP)
                                list[(size_t)grow * CAP + pos] =
                                    make_uint2(__float_as_uint(-2.f * av),
                                               (u32)(strip * 64 + u * 16 + lq * 4 + r));
                            ++pos;
                        }
                    }
            }
        }
    }
}

// ---------------------------------------------------------------- phase 2 (fused)
// R4-current VERBATIM except exact_r -> exact_r4 (float4 loads, bit-exact).
// One wave per row, 4 waves/block. Fast paths (no x-load, no exact work):
//   n==1: sole collected candidate wins (collection invariant).
//   unique margin-survivor: popc(ballot(vv<=mv+M2))==1 -> exact winner.
// Else: prune -> exact fp32 rescue -> packed shuffle-min tie-break.
// CAP-overflow bomb wall: 64 x exact_r4 ~ 27us (was ~170us scalar), and
// bombs run in parallel across 16K independent waves.
__launch_bounds__(256)
__global__ void phase2(const float* __restrict__ x, const float* __restrict__ emb,
                       const u32* __restrict__ cnt, const uint2* __restrict__ list,
                       float* __restrict__ outq, float* __restrict__ outp) {
    __shared__ float xs[4][DDIM];
    const int wid = threadIdx.x >> 6;
    const int row = blockIdx.x * 4 + wid;
    const int L   = threadIdx.x & 63;

    u32 n = cnt[row];
    u32 kstar;

    if (n == 1) {
        kstar = list[(size_t)row * CAP].y;    // unique candidate: no rescue needed
    } else {
        bool scan_all = (n > CAP);
        bool resolved = false;
        float vv = INFINITY; u32 kk = 0;
        bool surv = false;
        if (!scan_all) {
            if (L < (int)n) { uint2 e = list[(size_t)row * CAP + L]; vv = __uint_as_float(e.x); kk = e.y; }
            float mv = vv;
            #pragma unroll
            for (int o = 32; o; o >>= 1) mv = fminf(mv, __shfl_xor(mv, o, 64));
            surv = (L < (int)n) && (vv <= mv + MARGIN2);
            u64 bal = __ballot(surv);
            if (__popcll(bal) == 1) {          // unique margin-survivor = exact winner
                kstar = __shfl(kk, (int)(__ffsll(bal) - 1), 64);
                resolved = true;
            }
        }
        if (!resolved) {
            float4 v = ((const float4*)(x + (size_t)row * DDIM))[L];
            *(float4*)&xs[wid][L * 4] = v;
            double s = (double)v.x * v.x + (double)v.y * v.y + (double)v.z * v.z + (double)v.w * v.w;
            #pragma unroll
            for (int o = 32; o; o >>= 1) s += __shfl_xor(s, o, 64);
            float A = (float)s;

            u64 key = 0xFFFFFFFFFFFFFFFFull;
            if (!scan_all) {
                if (surv) {
                    float r = exact_r4(xs[wid], A, emb + (size_t)kk * DDIM);
                    key = ((u64)fkey(r) << 32) | (u64)kk;
                }
            } else {
                for (int c = 0; c < KCAND / 64; ++c) {
                    u32 k = (u32)(c * 64 + L);
                    float r = exact_r4(xs[wid], A, emb + (size_t)k * DDIM);
                    u64 cand = ((u64)fkey(r) << 32) | (u64)k;
                    key = (cand < key) ? cand : key;
                }
            }
            #pragma unroll
            for (int o = 32; o; o >>= 1) {
                u64 other = __shfl_xor(key, o, 64);
                key = (other < key) ? other : key;
            }
            kstar = (u32)(key & 0xFFFFFFFFull);
        }
    }

    float4 q = ((const float4*)(emb + (size_t)kstar * DDIM))[L];
    ((float4*)(outq + (size_t)row * DDIM))[L] = q;
    if (L == 0) outp[row] = (float)kstar;
}

// ---------------------------------------------------------------- launch
extern "C" void kernel_launch(void* const* d_in, const int* in_sizes, int n_in,
                              void* d_out, int out_size, void* d_ws, size_t ws_size,
                              hipStream_t stream) {
    const float* x   = (const float*)d_in[0];   // [65536, 256] fp32
    const float* emb = (const float*)d_in[1];   // [4096, 256] fp32
    float* outq = (float*)d_out;                      // [65536,256]
    float* outp = outq + (size_t)NROWS * DDIM;        // [65536]

    char* ws = (char*)d_ws;
    u32*   ebf  = (u32*)ws;                           // 2 MB (strip-major bf16)
    u32*   cnt  = (u32*)(ws + (2u << 20));            // 256 KB
    uint2* list = (uint2*)(ws + (3u << 20));          // 24 MB (total 27 MB)

    hipMemsetAsync(cnt, 0, (size_t)NROWS * sizeof(u32), stream);
    convert_e<<<512, 256, 0, stream>>>(emb, ebf);
    phase1<<<NROWS / ROWS_PB, 256, 0, stream>>>(x, ebf, cnt, list);
    phase2<<<NROWS / 4, 256, 0, stream>>>(x, emb, cnt, list, outq, outp);
}